// Round 1
// baseline (1677.308 us; speedup 1.0000x reference)
//
#include <hip/hip_runtime.h>
#include <math.h>

// ---------------------------------------------------------------------------
// HimNet multimode: 3 independent graph-GRU cells.
// B=8, N=1000, CIN=16, H=64, D=16, K=3, XIN=80, K*XIN=240, 2H=128.
//
// Per mode:
//   T0 = [x|state]  (node-major [n][b*80+c], 640 cols)
//   T1 = S@T0 ; T2 = 2*S@T1 - T0                  (cheb GEMMs, bf16 MFMA)
//   zr = sigmoid( fold(ew,Tk) @ Wg[3840,128] + bias )   (meta GEMM)
//     z -> ZS = z*state ; r -> R
//   SZ1 = S@ZS ; SZ2 = 2*S@SZ1 - ZS               (x-part of U-terms == Tk x-part)
//   hc = tanh( fold(ew,[Tk|Zk]) @ Wu[3840,64] + biasU )
//   h = r*state + (1-r)*hc  -> d_out
// ---------------------------------------------------------------------------

typedef __attribute__((ext_vector_type(8))) short s16x8;
typedef __attribute__((ext_vector_type(4))) float f32x4;

__device__ __forceinline__ unsigned int f2bf(float f) {
  union { float f; unsigned int u; } v; v.f = f;
  unsigned int r = v.u + 0x7FFFu + ((v.u >> 16) & 1u);  // RNE
  return r >> 16;
}
__device__ __forceinline__ unsigned int pack2bf(float a, float b) {
  return f2bf(a) | (f2bf(b) << 16);
}

// ---------------------------------------------------------------------------
// pack: T0[mode][n*640 + b*80 + c] = c<16 ? x[b,n,c] : state[b,n,c-16]
// ---------------------------------------------------------------------------
__global__ void pack_kernel(const float* __restrict__ x0, const float* __restrict__ x1,
                            const float* __restrict__ x2, const float* __restrict__ s0,
                            const float* __restrict__ s1, const float* __restrict__ s2,
                            float* __restrict__ T0) {
  int idx = blockIdx.x * blockDim.x + threadIdx.x;
  if (idx >= 3 * 640000) return;
  int mode = idx / 640000;
  int rem  = idx % 640000;
  int n = rem / 640;
  int q = rem % 640;
  int b = q / 80, c = q % 80;
  const float* x  = (mode == 0) ? x0 : (mode == 1) ? x1 : x2;
  const float* st = (mode == 0) ? s0 : (mode == 1) ? s1 : s2;
  float v = (c < 16) ? x[(b * 1000 + n) * 16 + c] : st[(b * 1000 + n) * 64 + (c - 16)];
  T0[idx] = v;
}

// ---------------------------------------------------------------------------
// bias: outB[mode][n*O + o] = sum_d emb[n,d]*me[mode,d]*Bp[d,o]
// ---------------------------------------------------------------------------
__global__ void bias_kernel(const float* __restrict__ e0, const float* __restrict__ e1,
                            const float* __restrict__ e2, const float* __restrict__ me,
                            const float* __restrict__ Bp, int O, float* __restrict__ outB) {
  int idx = blockIdx.x * blockDim.x + threadIdx.x;
  int total = 3 * 1000 * O;
  if (idx >= total) return;
  int mode = idx / (1000 * O);
  int rem  = idx % (1000 * O);
  int n = rem / O, o = rem % O;
  const float* emb = (mode == 0) ? e0 : (mode == 1) ? e1 : e2;
  float s = 0.f;
#pragma unroll
  for (int d = 0; d < 16; ++d)
    s += emb[n * 16 + d] * me[mode * 16 + d] * Bp[d * O + o];
  outB[idx] = s;
}

// ---------------------------------------------------------------------------
// cheb GEMM: Y = alpha*(S@X) + beta*Res ; M=K=1000, cols in {640,512}
// bf16 MFMA 16x16x32, block tile 128x64, BK=32, 256 thr (4 waves of 32x64).
// ---------------------------------------------------------------------------
struct ChebArgs {
  const float* S[3];
  const float* X[3];
  const float* Rs[3];
  float* Y[3];
};

#define ASTR 40  // bf16 elems/row: 32 + 8 pad (80 B, 16B-aligned rows)

__global__ __launch_bounds__(256) void cheb_gemm(ChebArgs args, int cols, float alpha, float beta) {
  const int mode = blockIdx.z;
  const float* __restrict__ S   = args.S[mode];
  const float* __restrict__ X   = args.X[mode];
  const float* __restrict__ Res = args.Rs[mode];
  float* __restrict__ Y         = args.Y[mode];

  __shared__ unsigned short As[128 * ASTR];  // [m][k]
  __shared__ unsigned short Bs[64 * ASTR];   // [n][k] (transposed)

  const int t = threadIdx.x;
  const int row0 = blockIdx.y * 128;
  const int col0 = blockIdx.x * 64;
  const int wid = t >> 6, lane = t & 63;
  const int quad = lane >> 4, l16 = lane & 15;
  const int wm = wid * 32;

  f32x4 acc[2][4];
#pragma unroll
  for (int a = 0; a < 2; ++a)
#pragma unroll
    for (int b = 0; b < 4; ++b) acc[a][b] = (f32x4){0.f, 0.f, 0.f, 0.f};

  for (int k0 = 0; k0 < 1024; k0 += 32) {
    // stage A (128x32 fp32 -> bf16), 8 float2 per thread
#pragma unroll
    for (int j = 0; j < 8; ++j) {
      int e = t + j * 256;       // 0..2047 (pairs)
      int m = e >> 4;            // 0..127
      int kp = (e & 15) * 2;     // 0..30
      int gr = row0 + m, gk = k0 + kp;
      float v0 = 0.f, v1 = 0.f;
      if (gr < 1000) {
        if (gk + 1 < 1000) { const float* p = S + gr * 1000 + gk; v0 = p[0]; v1 = p[1]; }
        else if (gk < 1000) { v0 = S[gr * 1000 + gk]; }
      }
      *(unsigned int*)&As[m * ASTR + kp] = pack2bf(v0, v1);
    }
    // stage B transposed (32xcols-slice -> Bs[n][k]), 4 pairs per thread
#pragma unroll
    for (int j = 0; j < 4; ++j) {
      int e = t + j * 256;       // 0..1023
      int n = e & 63;
      int kh = (e >> 6) * 2;     // 0..30
      int gk = k0 + kh;
      float v0 = (gk < 1000) ? X[gk * cols + col0 + n] : 0.f;
      float v1 = (gk + 1 < 1000) ? X[(gk + 1) * cols + col0 + n] : 0.f;
      *(unsigned int*)&Bs[n * ASTR + kh] = pack2bf(v0, v1);
    }
    __syncthreads();
    s16x8 af[2], bf[4];
#pragma unroll
    for (int mi = 0; mi < 2; ++mi)
      af[mi] = *(const s16x8*)&As[(wm + mi * 16 + l16) * ASTR + quad * 8];
#pragma unroll
    for (int ni = 0; ni < 4; ++ni)
      bf[ni] = *(const s16x8*)&Bs[(ni * 16 + l16) * ASTR + quad * 8];
#pragma unroll
    for (int mi = 0; mi < 2; ++mi)
#pragma unroll
      for (int ni = 0; ni < 4; ++ni)
        acc[mi][ni] = __builtin_amdgcn_mfma_f32_16x16x32_bf16(af[mi], bf[ni], acc[mi][ni], 0, 0, 0);
    __syncthreads();
  }
#pragma unroll
  for (int mi = 0; mi < 2; ++mi)
#pragma unroll
    for (int ni = 0; ni < 4; ++ni)
#pragma unroll
      for (int r = 0; r < 4; ++r) {
        int row = row0 + wm + mi * 16 + quad * 4 + r;
        int col = col0 + ni * 16 + l16;
        if (row < 1000) {
          float v = alpha * acc[mi][ni][r];
          if (beta != 0.f) v += beta * Res[row * cols + col];
          Y[row * cols + col] = v;
        }
      }
}

// ---------------------------------------------------------------------------
// meta GEMM (hypernet gate/update): rows r=(n*8+b) in [0,8000), K=3840 (d*240+i),
// A[r,dk] = ew[n,d]*Xg[n,b,i] generated during staging; B = Wg/Wu [3840][O].
// Block tile 64x64, BK=32, 128 thr (2 waves of 32x64).
// is_gate: epilogue sigmoid -> ZS/R ; else tanh -> h to d_out.
// ---------------------------------------------------------------------------
struct MetaArgs {
  const float* Tk[3][3];  // [cheb_k][mode]
  const float* Zk[3][3];  // [cheb_k][mode] (update only)
  const float* emb[3];
  const float* me;
  const float* W;          // [3840][O]
  const float* Bias[3];    // [1000][O] per mode
  const float* state[3];
  float* ZSo[3];
  float* Ro[3];
  float* out;
};

__global__ __launch_bounds__(128) void meta_gemm(MetaArgs A, int is_gate, int O) {
  const int mode = blockIdx.z;
  const int row0 = blockIdx.y * 64;
  const int col0 = blockIdx.x * 64;
  const int n0 = row0 >> 3;

  __shared__ unsigned short As[64 * ASTR];
  __shared__ unsigned short Bs[64 * ASTR];
  __shared__ float ewS[8][16];

  const int t = threadIdx.x;
  if (t < 128) {
    int nl = t >> 4, d = t & 15;
    ewS[nl][d] = A.emb[mode][(n0 + nl) * 16 + d] * A.me[mode * 16 + d];
  }
  __syncthreads();

  const int wid = t >> 6, lane = t & 63;
  const int quad = lane >> 4, l16 = lane & 15;
  const int wm = wid * 32;

  f32x4 acc[2][4];
#pragma unroll
  for (int a = 0; a < 2; ++a)
#pragma unroll
    for (int b = 0; b < 4; ++b) acc[a][b] = (f32x4){0.f, 0.f, 0.f, 0.f};

  for (int k0 = 0; k0 < 3840; k0 += 32) {
    // stage A: 64 rows x 32 dk; 8 float2 per thread, scaled by ew
#pragma unroll
    for (int j = 0; j < 8; ++j) {
      int e = t + j * 128;       // 0..1023 (pairs)
      int r = e >> 4;            // 0..63
      int u2 = (e & 15) * 2;     // 0..30 (even -> pair never crosses 80- or 16-boundaries)
      int dk = k0 + u2;
      int d = dk / 240;
      int i = dk % 240;
      int kc = i / 80, c = i % 80;
      int nl = r >> 3, b = r & 7;
      int n = n0 + nl;
      const float* src;
      if (is_gate || c < 16) src = A.Tk[kc][mode] + n * 640 + b * 80 + c;
      else                   src = A.Zk[kc][mode] + n * 512 + b * 64 + (c - 16);
      float ew = ewS[nl][d];
      float v0 = ew * src[0];
      float v1 = ew * src[1];
      *(unsigned int*)&As[r * ASTR + u2] = pack2bf(v0, v1);
    }
    // stage B transposed: W[k0..k0+32][col0..col0+64]
#pragma unroll
    for (int j = 0; j < 8; ++j) {
      int e = t + j * 128;       // 0..1023
      int n = e & 63;
      int kh = (e >> 6) * 2;     // 0..14 -> need 0..30: e>>6 in 0..15 -> ok
      int gk = k0 + kh;
      float v0 = A.W[gk * O + col0 + n];
      float v1 = A.W[(gk + 1) * O + col0 + n];
      *(unsigned int*)&Bs[n * ASTR + kh] = pack2bf(v0, v1);
    }
    __syncthreads();
    s16x8 af[2], bf[4];
#pragma unroll
    for (int mi = 0; mi < 2; ++mi)
      af[mi] = *(const s16x8*)&As[(wm + mi * 16 + l16) * ASTR + quad * 8];
#pragma unroll
    for (int ni = 0; ni < 4; ++ni)
      bf[ni] = *(const s16x8*)&Bs[(ni * 16 + l16) * ASTR + quad * 8];
#pragma unroll
    for (int mi = 0; mi < 2; ++mi)
#pragma unroll
      for (int ni = 0; ni < 4; ++ni)
        acc[mi][ni] = __builtin_amdgcn_mfma_f32_16x16x32_bf16(af[mi], bf[ni], acc[mi][ni], 0, 0, 0);
    __syncthreads();
  }

#pragma unroll
  for (int mi = 0; mi < 2; ++mi)
#pragma unroll
    for (int ni = 0; ni < 4; ++ni)
#pragma unroll
      for (int r = 0; r < 4; ++r) {
        int gr = row0 + wm + mi * 16 + quad * 4 + r;   // < 8000 always
        int og = col0 + ni * 16 + l16;
        int n = gr >> 3, b = gr & 7;
        float pre = acc[mi][ni][r] + A.Bias[mode][n * O + og];
        if (is_gate) {
          float s = 1.f / (1.f + __expf(-pre));
          if (og < 64) {
            float st = A.state[mode][(b * 1000 + n) * 64 + og];
            A.ZSo[mode][n * 512 + b * 64 + og] = s * st;
          } else {
            A.Ro[mode][n * 512 + b * 64 + (og - 64)] = s;
          }
        } else {
          float hc = tanhf(pre);
          float rr = A.Ro[mode][n * 512 + b * 64 + og];
          float st = A.state[mode][(b * 1000 + n) * 64 + og];
          A.out[mode * 512000 + (b * 1000 + n) * 64 + og] = rr * st + (1.f - rr) * hc;
        }
      }
}

// ---------------------------------------------------------------------------
extern "C" void kernel_launch(void* const* d_in, const int* in_sizes, int n_in,
                              void* d_out, int out_size, void* d_ws, size_t ws_size,
                              hipStream_t stream) {
  const float* x[3]   = {(const float*)d_in[0], (const float*)d_in[1], (const float*)d_in[2]};
  const float* st[3]  = {(const float*)d_in[3], (const float*)d_in[4], (const float*)d_in[5]};
  const float* S[3]   = {(const float*)d_in[6], (const float*)d_in[7], (const float*)d_in[8]};
  const float* emb[3] = {(const float*)d_in[9], (const float*)d_in[10], (const float*)d_in[11]};
  const float* me = (const float*)d_in[12];
  const float* Wg = (const float*)d_in[13];
  const float* Bg = (const float*)d_in[14];
  const float* Wu = (const float*)d_in[15];
  const float* Bu = (const float*)d_in[16];
  float* out = (float*)d_out;

  float* ws = (float*)d_ws;
  float* T0 = ws;                    // 3*640000
  float* T1 = T0 + 1920000;
  float* T2 = T1 + 1920000;
  float* ZS = T2 + 1920000;          // 3*512000
  float* SZ1 = ZS + 1536000;
  float* SZ2 = SZ1 + 1536000;
  float* Rb  = SZ2 + 1536000;
  float* BiG = Rb + 1536000;         // 3*128000
  float* BiU = BiG + 384000;         // 3*64000

  // 1. pack T0
  pack_kernel<<<7500, 256, 0, stream>>>(x[0], x[1], x[2], st[0], st[1], st[2], T0);
  // 2-3. biases
  bias_kernel<<<1500, 256, 0, stream>>>(emb[0], emb[1], emb[2], me, Bg, 128, BiG);
  bias_kernel<<<750, 256, 0, stream>>>(emb[0], emb[1], emb[2], me, Bu, 64, BiU);

  // 4. T1 = S@T0
  {
    ChebArgs a;
    for (int m = 0; m < 3; ++m) { a.S[m] = S[m]; a.X[m] = T0 + m * 640000; a.Rs[m] = T0 + m * 640000; a.Y[m] = T1 + m * 640000; }
    cheb_gemm<<<dim3(10, 8, 3), 256, 0, stream>>>(a, 640, 1.f, 0.f);
  }
  // 5. T2 = 2*S@T1 - T0
  {
    ChebArgs a;
    for (int m = 0; m < 3; ++m) { a.S[m] = S[m]; a.X[m] = T1 + m * 640000; a.Rs[m] = T0 + m * 640000; a.Y[m] = T2 + m * 640000; }
    cheb_gemm<<<dim3(10, 8, 3), 256, 0, stream>>>(a, 640, 2.f, -1.f);
  }
  // 6. gate
  {
    MetaArgs a;
    for (int m = 0; m < 3; ++m) {
      a.Tk[0][m] = T0 + m * 640000; a.Tk[1][m] = T1 + m * 640000; a.Tk[2][m] = T2 + m * 640000;
      a.Zk[0][m] = ZS + m * 512000; a.Zk[1][m] = SZ1 + m * 512000; a.Zk[2][m] = SZ2 + m * 512000;
      a.emb[m] = emb[m]; a.Bias[m] = BiG + m * 128000; a.state[m] = st[m];
      a.ZSo[m] = ZS + m * 512000; a.Ro[m] = Rb + m * 512000;
    }
    a.me = me; a.W = Wg; a.out = out;
    meta_gemm<<<dim3(2, 125, 3), 128, 0, stream>>>(a, 1, 128);
  }
  // 7. SZ1 = S@ZS
  {
    ChebArgs a;
    for (int m = 0; m < 3; ++m) { a.S[m] = S[m]; a.X[m] = ZS + m * 512000; a.Rs[m] = ZS + m * 512000; a.Y[m] = SZ1 + m * 512000; }
    cheb_gemm<<<dim3(8, 8, 3), 256, 0, stream>>>(a, 512, 1.f, 0.f);
  }
  // 8. SZ2 = 2*S@SZ1 - ZS
  {
    ChebArgs a;
    for (int m = 0; m < 3; ++m) { a.S[m] = S[m]; a.X[m] = SZ1 + m * 512000; a.Rs[m] = ZS + m * 512000; a.Y[m] = SZ2 + m * 512000; }
    cheb_gemm<<<dim3(8, 8, 3), 256, 0, stream>>>(a, 512, 2.f, -1.f);
  }
  // 9. update -> h
  {
    MetaArgs a;
    for (int m = 0; m < 3; ++m) {
      a.Tk[0][m] = T0 + m * 640000; a.Tk[1][m] = T1 + m * 640000; a.Tk[2][m] = T2 + m * 640000;
      a.Zk[0][m] = ZS + m * 512000; a.Zk[1][m] = SZ1 + m * 512000; a.Zk[2][m] = SZ2 + m * 512000;
      a.emb[m] = emb[m]; a.Bias[m] = BiU + m * 64000; a.state[m] = st[m];
      a.ZSo[m] = ZS + m * 512000; a.Ro[m] = Rb + m * 512000;
    }
    a.me = me; a.W = Wu; a.out = out;
    meta_gemm<<<dim3(1, 125, 3), 128, 0, stream>>>(a, 0, 64);
  }
}

// Round 2
// 814.696 us; speedup vs baseline: 2.0588x; 2.0588x over previous
//
#include <hip/hip_runtime.h>
#include <math.h>

// ---------------------------------------------------------------------------
// HimNet multimode: 3 independent graph-GRU cells.
// B=8, N=1000, CIN=16, H=64, D=16, K=3, XIN=80, K*XIN=240, 2H=128.
//
// Pipeline:
//   T0 = [x|state] (fp32, node-major [n][b*80+c], 640 cols)
//   T1 = S@T0 ; T2 = 2*S@T1 - T0                    (cheb GEMMs, bf16 MFMA)
//   Ag = bf16 pack of [T0|T1|T2] as [8000][240]
//   G  = Ag @ Bt   (Bt[(o*16+d)][i] = Wg[d,i,o])    -> epilogue: out[r,o] =
//        sigmoid( sum_d ew[n,d]*G[r,o*16+d] + bias ) -> z->ZS=z*state, r->Rb
//   SZ1 = S@ZS ; SZ2 = 2*S@SZ1 - ZS
//   Au = bf16 pack of update terms [8000][240]
//   hc = tanh(meta2(Au, Wu)) ; h = r*state+(1-r)*hc -> d_out
// ---------------------------------------------------------------------------

typedef __attribute__((ext_vector_type(8))) short s16x8;
typedef __attribute__((ext_vector_type(4))) float f32x4;

__device__ __forceinline__ unsigned int f2bf(float f) {
  union { float f; unsigned int u; } v; v.f = f;
  unsigned int r = v.u + 0x7FFFu + ((v.u >> 16) & 1u);  // RNE
  return r >> 16;
}
__device__ __forceinline__ unsigned int pack2bf(float a, float b) {
  return f2bf(a) | (f2bf(b) << 16);
}

// ---------------------------------------------------------------------------
// pack: T0[mode][n*640 + b*80 + c] = c<16 ? x[b,n,c] : state[b,n,c-16]
// ---------------------------------------------------------------------------
__global__ void pack_kernel(const float* __restrict__ x0, const float* __restrict__ x1,
                            const float* __restrict__ x2, const float* __restrict__ s0,
                            const float* __restrict__ s1, const float* __restrict__ s2,
                            float* __restrict__ T0) {
  int idx = blockIdx.x * blockDim.x + threadIdx.x;
  if (idx >= 3 * 640000) return;
  int mode = idx / 640000;
  int rem  = idx % 640000;
  int n = rem / 640;
  int q = rem % 640;
  int b = q / 80, c = q % 80;
  const float* x  = (mode == 0) ? x0 : (mode == 1) ? x1 : x2;
  const float* st = (mode == 0) ? s0 : (mode == 1) ? s1 : s2;
  float v = (c < 16) ? x[(b * 1000 + n) * 16 + c] : st[(b * 1000 + n) * 64 + (c - 16)];
  T0[idx] = v;
}

// ---------------------------------------------------------------------------
// bias: outB[mode][n*O + o] = sum_d emb[n,d]*me[mode,d]*Bp[d,o]
// ---------------------------------------------------------------------------
__global__ void bias_kernel(const float* __restrict__ e0, const float* __restrict__ e1,
                            const float* __restrict__ e2, const float* __restrict__ me,
                            const float* __restrict__ Bp, int O, float* __restrict__ outB) {
  int idx = blockIdx.x * blockDim.x + threadIdx.x;
  int total = 3 * 1000 * O;
  if (idx >= total) return;
  int mode = idx / (1000 * O);
  int rem  = idx % (1000 * O);
  int n = rem / O, o = rem % O;
  const float* emb = (mode == 0) ? e0 : (mode == 1) ? e1 : e2;
  float s = 0.f;
#pragma unroll
  for (int d = 0; d < 16; ++d)
    s += emb[n * 16 + d] * me[mode * 16 + d] * Bp[d * O + o];
  outB[idx] = s;
}

// ---------------------------------------------------------------------------
// packW: Bt[(o*16+d)][k] = bf16(W[d,k,o]) for k<240, 0 for 240<=k<256.
// Gate: O=128 (2048 cols); Update: O=64 (1024 cols). One launch covers both.
// ---------------------------------------------------------------------------
__global__ void packW_kernel(const float* __restrict__ Wg, const float* __restrict__ Wu,
                             unsigned short* __restrict__ BtG, unsigned short* __restrict__ BtU) {
  int idx = blockIdx.x * blockDim.x + threadIdx.x;
  if (idx >= (2048 + 1024) * 256) return;
  if (idx < 2048 * 256) {
    int col = idx >> 8, k = idx & 255;
    int o = col >> 4, d = col & 15;
    BtG[idx] = (k < 240) ? (unsigned short)f2bf(Wg[d * 240 * 128 + k * 128 + o]) : (unsigned short)0;
  } else {
    int i2 = idx - 2048 * 256;
    int col = i2 >> 8, k = i2 & 255;
    int o = col >> 4, d = col & 15;
    BtU[i2] = (k < 240) ? (unsigned short)f2bf(Wu[d * 240 * 64 + k * 64 + o]) : (unsigned short)0;
  }
}

// ---------------------------------------------------------------------------
// packA (gate): Ag[mode][r*240 + kc*80 + c] = bf16(Tkc[mode][n*640 + b*80 + c])
// r = n*8+b.
// ---------------------------------------------------------------------------
__global__ void packA_gate(const float* __restrict__ T0, const float* __restrict__ T1,
                           const float* __restrict__ T2, unsigned short* __restrict__ Ag) {
  int idx = blockIdx.x * blockDim.x + threadIdx.x;
  if (idx >= 3 * 8000 * 240) return;
  int mode = idx / 1920000;
  int rem  = idx % 1920000;
  int r = rem / 240, i = rem % 240;
  int kc = i / 80, c = i % 80;
  int n = r >> 3, b = r & 7;
  const float* T = (kc == 0) ? T0 : (kc == 1) ? T1 : T2;
  Ag[idx] = (unsigned short)f2bf(T[mode * 640000 + n * 640 + b * 80 + c]);
}

// ---------------------------------------------------------------------------
// packA (update): c<16 from Tkc x-part; c>=16 from {ZS,SZ1,SZ2} (512-col layout)
// ---------------------------------------------------------------------------
__global__ void packA_up(const float* __restrict__ T0, const float* __restrict__ T1,
                         const float* __restrict__ T2, const float* __restrict__ Z0,
                         const float* __restrict__ Z1, const float* __restrict__ Z2,
                         unsigned short* __restrict__ Au) {
  int idx = blockIdx.x * blockDim.x + threadIdx.x;
  if (idx >= 3 * 8000 * 240) return;
  int mode = idx / 1920000;
  int rem  = idx % 1920000;
  int r = rem / 240, i = rem % 240;
  int kc = i / 80, c = i % 80;
  int n = r >> 3, b = r & 7;
  float v;
  if (c < 16) {
    const float* T = (kc == 0) ? T0 : (kc == 1) ? T1 : T2;
    v = T[mode * 640000 + n * 640 + b * 80 + c];
  } else {
    const float* Z = (kc == 0) ? Z0 : (kc == 1) ? Z1 : Z2;
    v = Z[mode * 512000 + n * 512 + b * 64 + (c - 16)];
  }
  Au[idx] = (unsigned short)f2bf(v);
}

// ---------------------------------------------------------------------------
// cheb GEMM: Y = alpha*(S@X) + beta*Res ; M=K=1000, cols in {640,512}, fp32 io
// bf16 MFMA 16x16x32, block tile 128x64, BK=32, 256 thr (4 waves of 32x64).
// ---------------------------------------------------------------------------
struct ChebArgs {
  const float* S[3];
  const float* X[3];
  const float* Rs[3];
  float* Y[3];
};

#define ASTR 40  // bf16 elems/row: 32 + 8 pad (80 B, 16B-aligned rows)

__global__ __launch_bounds__(256) void cheb_gemm(ChebArgs args, int cols, float alpha, float beta) {
  const int mode = blockIdx.z;
  const float* __restrict__ S   = args.S[mode];
  const float* __restrict__ X   = args.X[mode];
  const float* __restrict__ Res = args.Rs[mode];
  float* __restrict__ Y         = args.Y[mode];

  __shared__ unsigned short As[128 * ASTR];  // [m][k]
  __shared__ unsigned short Bs[64 * ASTR];   // [n][k] (transposed)

  const int t = threadIdx.x;
  const int row0 = blockIdx.y * 128;
  const int col0 = blockIdx.x * 64;
  const int wid = t >> 6, lane = t & 63;
  const int quad = lane >> 4, l16 = lane & 15;
  const int wm = wid * 32;

  f32x4 acc[2][4];
#pragma unroll
  for (int a = 0; a < 2; ++a)
#pragma unroll
    for (int b = 0; b < 4; ++b) acc[a][b] = (f32x4){0.f, 0.f, 0.f, 0.f};

  for (int k0 = 0; k0 < 1024; k0 += 32) {
    // stage A (128x32 fp32 -> bf16), 8 float2 per thread
#pragma unroll
    for (int j = 0; j < 8; ++j) {
      int e = t + j * 256;       // 0..2047 (pairs)
      int m = e >> 4;            // 0..127
      int kp = (e & 15) * 2;     // 0..30
      int gr = row0 + m, gk = k0 + kp;
      float v0 = 0.f, v1 = 0.f;
      if (gr < 1000) {
        if (gk + 1 < 1000) { const float* p = S + gr * 1000 + gk; v0 = p[0]; v1 = p[1]; }
        else if (gk < 1000) { v0 = S[gr * 1000 + gk]; }
      }
      *(unsigned int*)&As[m * ASTR + kp] = pack2bf(v0, v1);
    }
    // stage B transposed (32xcols-slice -> Bs[n][k]), 4 pairs per thread
#pragma unroll
    for (int j = 0; j < 4; ++j) {
      int e = t + j * 256;       // 0..1023
      int n = e & 63;
      int kh = (e >> 6) * 2;     // 0..30
      int gk = k0 + kh;
      float v0 = (gk < 1000) ? X[gk * cols + col0 + n] : 0.f;
      float v1 = (gk + 1 < 1000) ? X[(gk + 1) * cols + col0 + n] : 0.f;
      *(unsigned int*)&Bs[n * ASTR + kh] = pack2bf(v0, v1);
    }
    __syncthreads();
    s16x8 af[2], bf[4];
#pragma unroll
    for (int mi = 0; mi < 2; ++mi)
      af[mi] = *(const s16x8*)&As[(wm + mi * 16 + l16) * ASTR + quad * 8];
#pragma unroll
    for (int ni = 0; ni < 4; ++ni)
      bf[ni] = *(const s16x8*)&Bs[(ni * 16 + l16) * ASTR + quad * 8];
#pragma unroll
    for (int mi = 0; mi < 2; ++mi)
#pragma unroll
      for (int ni = 0; ni < 4; ++ni)
        acc[mi][ni] = __builtin_amdgcn_mfma_f32_16x16x32_bf16(af[mi], bf[ni], acc[mi][ni], 0, 0, 0);
    __syncthreads();
  }
#pragma unroll
  for (int mi = 0; mi < 2; ++mi)
#pragma unroll
    for (int ni = 0; ni < 4; ++ni)
#pragma unroll
      for (int r = 0; r < 4; ++r) {
        int row = row0 + wm + mi * 16 + quad * 4 + r;
        int col = col0 + ni * 16 + l16;
        if (row < 1000) {
          float v = alpha * acc[mi][ni][r];
          if (beta != 0.f) v += beta * Res[row * cols + col];
          Y[row * cols + col] = v;
        }
      }
}

// ---------------------------------------------------------------------------
// meta2: G = A[8000x240] @ Bt[(O*16) x 240]^T (K padded to 256), then fused
// epilogue out[r,o] = act( sum_d ew[n,d]*G[r,o*16+d] + bias[n,o] ).
// Tile 128x64 (G-cols), 256 thr, 4 waves of 32 rows; 8 K-iters of BK=32.
// ---------------------------------------------------------------------------
struct Meta2Args {
  const unsigned short* Ag;   // [3][8000][240] bf16
  const unsigned short* Bt;   // [O*16][256] bf16 (K pre-padded with zeros)
  const float* emb[3];
  const float* me;
  const float* Bias;          // [3][1000][O]
  const float* state[3];
  float* ZS;                  // [3][512000]
  float* Rb;                  // [3][512000]
  float* out;
};

__global__ __launch_bounds__(256) void meta2(Meta2Args A, int is_gate, int O) {
  const int mode = blockIdx.z;
  const int row0 = blockIdx.y * 128;
  const int col0 = blockIdx.x * 64;   // in G-cols (o*16+d)
  const int n0 = row0 >> 3;           // 16 nodes per block

  __shared__ float Epi[128][65];      // 33.3 KB; staging aliases into it
  __shared__ float ewS[16][16];
  unsigned short* As = (unsigned short*)&Epi[0][0];  // [128][ASTR]
  unsigned short* Bs = As + 128 * ASTR;              // [64][ASTR]

  const int t = threadIdx.x;
  {
    int nl = t >> 4, d = t & 15;
    if (t < 256) {
      int n = n0 + nl;
      ewS[nl][d] = (n < 1000) ? A.emb[mode][n * 16 + d] * A.me[mode * 16 + d] : 0.f;
    }
  }

  const unsigned short* Ag = A.Ag + (size_t)mode * 8000 * 240;
  const int wid = t >> 6, lane = t & 63;
  const int quad = lane >> 4, l16 = lane & 15;
  const int wm = wid * 32;

  f32x4 acc[2][4];
#pragma unroll
  for (int a = 0; a < 2; ++a)
#pragma unroll
    for (int b = 0; b < 4; ++b) acc[a][b] = (f32x4){0.f, 0.f, 0.f, 0.f};

  for (int k0 = 0; k0 < 256; k0 += 32) {
    // A: 128 rows x 32 k, ushort4 (8B) x4 per thread
#pragma unroll
    for (int j = 0; j < 4; ++j) {
      int idx = t + j * 256;           // 0..1023
      int m = idx >> 3;                // 0..127
      int k4 = (idx & 7) * 4;          // 0..28
      int gr = row0 + m, gk = k0 + k4;
      unsigned long long v = 0ull;
      if (gr < 8000 && gk < 240)
        v = *(const unsigned long long*)(Ag + (size_t)gr * 240 + gk);
      *(unsigned long long*)&As[m * ASTR + k4] = v;
    }
    // B: 64 cols x 32 k, ushort4 x2 per thread (pre-padded, no guards)
#pragma unroll
    for (int j = 0; j < 2; ++j) {
      int idx = t + j * 256;           // 0..511
      int nn = idx >> 3;               // 0..63
      int k4 = (idx & 7) * 4;
      unsigned long long v = *(const unsigned long long*)(A.Bt + (size_t)(col0 + nn) * 256 + k0 + k4);
      *(unsigned long long*)&Bs[nn * ASTR + k4] = v;
    }
    __syncthreads();
    s16x8 af[2], bf[4];
#pragma unroll
    for (int mi = 0; mi < 2; ++mi)
      af[mi] = *(const s16x8*)&As[(wm + mi * 16 + l16) * ASTR + quad * 8];
#pragma unroll
    for (int ni = 0; ni < 4; ++ni)
      bf[ni] = *(const s16x8*)&Bs[(ni * 16 + l16) * ASTR + quad * 8];
#pragma unroll
    for (int mi = 0; mi < 2; ++mi)
#pragma unroll
      for (int ni = 0; ni < 4; ++ni)
        acc[mi][ni] = __builtin_amdgcn_mfma_f32_16x16x32_bf16(af[mi], bf[ni], acc[mi][ni], 0, 0, 0);
    __syncthreads();
  }

  // epilogue: scale by ew, dump to LDS (re-using staging space), d-reduce
#pragma unroll
  for (int mi = 0; mi < 2; ++mi)
#pragma unroll
    for (int ni = 0; ni < 4; ++ni)
#pragma unroll
      for (int r = 0; r < 4; ++r) {
        int row = wm + mi * 16 + quad * 4 + r;       // 0..127
        Epi[row][ni * 16 + l16] = acc[mi][ni][r] * ewS[row >> 3][l16];
      }
  __syncthreads();

#pragma unroll
  for (int j = 0; j < 2; ++j) {
    int oi = t + j * 256;      // 0..511 = 128 rows x 4 o
    int row = oi >> 2;
    int ol = oi & 3;
    float s = 0.f;
#pragma unroll
    for (int d = 0; d < 16; ++d) s += Epi[row][ol * 16 + d];
    int gr = row0 + row;
    if (gr < 8000) {
      int n = gr >> 3, b = gr & 7;
      int og = (col0 >> 4) + ol;
      float pre = s + A.Bias[(size_t)mode * 1000 * O + n * O + og];
      if (is_gate) {
        float sg = 1.f / (1.f + __expf(-pre));
        if (og < 64) {
          float st = A.state[mode][(b * 1000 + n) * 64 + og];
          A.ZS[(size_t)mode * 512000 + n * 512 + b * 64 + og] = sg * st;
        } else {
          A.Rb[(size_t)mode * 512000 + n * 512 + b * 64 + (og - 64)] = sg;
        }
      } else {
        float hc = tanhf(pre);
        float rr = A.Rb[(size_t)mode * 512000 + n * 512 + b * 64 + og];
        float st = A.state[mode][(b * 1000 + n) * 64 + og];
        A.out[(size_t)mode * 512000 + (b * 1000 + n) * 64 + og] = rr * st + (1.f - rr) * hc;
      }
    }
  }
}

// ---------------------------------------------------------------------------
extern "C" void kernel_launch(void* const* d_in, const int* in_sizes, int n_in,
                              void* d_out, int out_size, void* d_ws, size_t ws_size,
                              hipStream_t stream) {
  const float* x[3]   = {(const float*)d_in[0], (const float*)d_in[1], (const float*)d_in[2]};
  const float* st[3]  = {(const float*)d_in[3], (const float*)d_in[4], (const float*)d_in[5]};
  const float* S[3]   = {(const float*)d_in[6], (const float*)d_in[7], (const float*)d_in[8]};
  const float* emb[3] = {(const float*)d_in[9], (const float*)d_in[10], (const float*)d_in[11]};
  const float* me = (const float*)d_in[12];
  const float* Wg = (const float*)d_in[13];
  const float* Bg = (const float*)d_in[14];
  const float* Wu = (const float*)d_in[15];
  const float* Bu = (const float*)d_in[16];
  float* out = (float*)d_out;

  float* ws = (float*)d_ws;
  float* T0 = ws;                    // 3*640000
  float* T1 = T0 + 1920000;
  float* T2 = T1 + 1920000;
  float* ZS = T2 + 1920000;          // 3*512000
  float* SZ1 = ZS + 1536000;
  float* SZ2 = SZ1 + 1536000;
  float* Rb  = SZ2 + 1536000;
  float* BiG = Rb + 1536000;         // 3*128000
  float* BiU = BiG + 384000;         // 3*64000
  unsigned short* BtG = (unsigned short*)(BiU + 192000);  // 2048*256
  unsigned short* BtU = BtG + 2048 * 256;                 // 1024*256
  unsigned short* Ag  = BtU + 1024 * 256;                 // 3*8000*240
  unsigned short* Au  = Ag + 3 * 8000 * 240;              // 3*8000*240

  // independent prep
  pack_kernel<<<7500, 256, 0, stream>>>(x[0], x[1], x[2], st[0], st[1], st[2], T0);
  bias_kernel<<<1500, 256, 0, stream>>>(emb[0], emb[1], emb[2], me, Bg, 128, BiG);
  bias_kernel<<<750, 256, 0, stream>>>(emb[0], emb[1], emb[2], me, Bu, 64, BiU);
  packW_kernel<<<3072, 256, 0, stream>>>(Wg, Wu, BtG, BtU);

  // cheb T1 = S@T0 ; T2 = 2*S@T1 - T0
  {
    ChebArgs a;
    for (int m = 0; m < 3; ++m) { a.S[m] = S[m]; a.X[m] = T0 + m * 640000; a.Rs[m] = T0 + m * 640000; a.Y[m] = T1 + m * 640000; }
    cheb_gemm<<<dim3(10, 8, 3), 256, 0, stream>>>(a, 640, 1.f, 0.f);
  }
  {
    ChebArgs a;
    for (int m = 0; m < 3; ++m) { a.S[m] = S[m]; a.X[m] = T1 + m * 640000; a.Rs[m] = T0 + m * 640000; a.Y[m] = T2 + m * 640000; }
    cheb_gemm<<<dim3(10, 8, 3), 256, 0, stream>>>(a, 640, 2.f, -1.f);
  }

  // gate meta
  packA_gate<<<22500, 256, 0, stream>>>(T0, T1, T2, Ag);
  {
    Meta2Args a;
    a.Ag = Ag; a.Bt = BtG; a.me = me; a.Bias = BiG; a.out = out;
    a.ZS = ZS; a.Rb = Rb;
    for (int m = 0; m < 3; ++m) { a.emb[m] = emb[m]; a.state[m] = st[m]; }
    meta2<<<dim3(32, 63, 3), 256, 0, stream>>>(a, 1, 128);
  }

  // cheb on ZS
  {
    ChebArgs a;
    for (int m = 0; m < 3; ++m) { a.S[m] = S[m]; a.X[m] = ZS + m * 512000; a.Rs[m] = ZS + m * 512000; a.Y[m] = SZ1 + m * 512000; }
    cheb_gemm<<<dim3(8, 8, 3), 256, 0, stream>>>(a, 512, 1.f, 0.f);
  }
  {
    ChebArgs a;
    for (int m = 0; m < 3; ++m) { a.S[m] = S[m]; a.X[m] = SZ1 + m * 512000; a.Rs[m] = ZS + m * 512000; a.Y[m] = SZ2 + m * 512000; }
    cheb_gemm<<<dim3(8, 8, 3), 256, 0, stream>>>(a, 512, 2.f, -1.f);
  }

  // update meta -> h
  packA_up<<<22500, 256, 0, stream>>>(T0, T1, T2, ZS, SZ1, SZ2, Au);
  {
    Meta2Args a;
    a.Ag = Au; a.Bt = BtU; a.me = me; a.Bias = BiU; a.out = out;
    a.ZS = ZS; a.Rb = Rb;
    for (int m = 0; m < 3; ++m) { a.emb[m] = emb[m]; a.state[m] = st[m]; }
    meta2<<<dim3(16, 63, 3), 256, 0, stream>>>(a, 0, 64);
  }
}

// Round 3
// 333.506 us; speedup vs baseline: 5.0293x; 2.4428x over previous
//
#include <hip/hip_runtime.h>
#include <math.h>

// ---------------------------------------------------------------------------
// HimNet multimode v3. B=8,N=1000,CIN=16,H=64,D=16,K=3,XIN=80,K*XIN=240,2H=128
//
// All GEMM operands pre-packed bf16; cheb GEMMs run feature-major:
//   T1t[f][n] = sum_k Xt[f][k] * S[n][k]   (Xt = T0 transposed, f=b*80+c)
// so A and B frags are both k-contiguous -> pure global_load_lds staging.
// Cheb epilogues write bf16 straight into the meta GEMM A-matrices:
//   Ag  [8000][256]: gate A  = [T0|T1|T2]           (rows r=n*8+b, k=kc*80+c)
//   AgU [8000][256]: update A= [x|zs chain]         (written by prep/metaG/chebs)
// meta2: G = A @ Bt^T (Bt[(o*16+d)][256]), epilogue reduces d with ew[n,d].
// ---------------------------------------------------------------------------

typedef __attribute__((ext_vector_type(8))) short s16x8;
typedef __attribute__((ext_vector_type(4))) float f32x4;
typedef unsigned short u16;
typedef unsigned int u32;
typedef unsigned long long u64;

__device__ __forceinline__ u32 f2bf(float f) {
  union { float f; u32 u; } v; v.f = f;
  return (v.u + 0x7FFFu + ((v.u >> 16) & 1u)) >> 16;  // RNE
}
__device__ __forceinline__ float bf2f(u16 h) {
  union { u32 u; float f; } v; v.u = (u32)h << 16; return v.f;
}
__device__ __forceinline__ void glds16(const u16* g, u16* l) {
  __builtin_amdgcn_global_load_lds(
      (const __attribute__((address_space(1))) void*)g,
      (__attribute__((address_space(3))) void*)l, 16, 0, 0);
}

// ---------------------------------------------------------------------------
// prep: build S16[3][1024][1024], Xt[3][640][1024], Ag kc0 slots, AgU x-slots,
// K-pads of Ag/AgU, and n-pad rows of T1t/ZSt/SZ1t. One elem per thread.
// ---------------------------------------------------------------------------
#define E0 3145728
#define E1 1966080
#define E2 1920000
#define E3 384000
#define E4 384000
#define E5 384000
#define E6 119808
// total = 8303616 = 32436 * 256

struct PrepArgs {
  const float* x[3]; const float* st[3]; const float* S[3];
  u16 *S16, *Xt, *Ag, *AgU, *T1t, *ZSt, *SZ1t;
};

__global__ void prep(PrepArgs P) {
  long idx = (long)blockIdx.x * 256 + threadIdx.x;
  if (idx < E0) {  // S16 incl pads
    int m = (int)(idx >> 20); int rem = (int)(idx & 1048575);
    int n = rem >> 10, k = rem & 1023;
    float v = (n < 1000 && k < 1000) ? P.S[m][n * 1000 + k] : 0.f;
    P.S16[(size_t)m * 1048576 + rem] = (u16)f2bf(v); return;
  }
  idx -= E0;
  if (idx < E1) {  // Xt incl n-pads
    int m = (int)(idx / 655360); int rem = (int)(idx % 655360);
    int col = rem >> 10, nn = rem & 1023;
    int b = col / 80, c = col % 80;
    float v = 0.f;
    if (nn < 1000) v = (c < 16) ? P.x[m][(b * 1000 + nn) * 16 + c]
                                : P.st[m][(b * 1000 + nn) * 64 + c - 16];
    P.Xt[(size_t)m * 655360 + rem] = (u16)f2bf(v); return;
  }
  idx -= E1;
  if (idx < E2) {  // Ag kc0 (cols 0..79)
    int m = (int)(idx / 640000); int rem = (int)(idx % 640000);
    int r = rem / 80, c = rem % 80;
    int n = r >> 3, b = r & 7;
    float v = (c < 16) ? P.x[m][(b * 1000 + n) * 16 + c]
                       : P.st[m][(b * 1000 + n) * 64 + c - 16];
    P.Ag[(size_t)m * 2048000 + (size_t)r * 256 + c] = (u16)f2bf(v); return;
  }
  idx -= E2;
  if (idx < E3) {  // Ag K-pad 240..255
    int m = (int)(idx / 128000); int rem = (int)(idx % 128000);
    int r = rem / 16, c = 240 + rem % 16;
    P.Ag[(size_t)m * 2048000 + (size_t)r * 256 + c] = 0; return;
  }
  idx -= E3;
  if (idx < E4) {  // AgU kc0 x-part (cols 0..15)
    int m = (int)(idx / 128000); int rem = (int)(idx % 128000);
    int r = rem / 16, c = rem % 16;
    int n = r >> 3, b = r & 7;
    P.AgU[(size_t)m * 2048000 + (size_t)r * 256 + c] =
        (u16)f2bf(P.x[m][(b * 1000 + n) * 16 + c]); return;
  }
  idx -= E4;
  if (idx < E5) {  // AgU K-pad
    int m = (int)(idx / 128000); int rem = (int)(idx % 128000);
    int r = rem / 16, c = 240 + rem % 16;
    P.AgU[(size_t)m * 2048000 + (size_t)r * 256 + c] = 0; return;
  }
  idx -= E5;
  if (idx < E6) {  // n-pad rows (k=1000..1023) of T1t/ZSt/SZ1t
    int m = (int)(idx / 39936); int rem = (int)(idx % 39936);
    if (rem < 15360) { int col = rem / 24, j = rem % 24;
      P.T1t[(size_t)m * 655360 + col * 1024 + 1000 + j] = 0; }
    else if (rem < 27648) { int e = rem - 15360; int col = e / 24, j = e % 24;
      P.ZSt[(size_t)m * 524288 + col * 1024 + 1000 + j] = 0; }
    else { int e = rem - 27648; int col = e / 24, j = e % 24;
      P.SZ1t[(size_t)m * 524288 + col * 1024 + 1000 + j] = 0; }
    return;
  }
}

// ---------------------------------------------------------------------------
// bias: outB[mode][n*O+o] = sum_d emb[n,d]*me[mode,d]*Bp[d,o]
// ---------------------------------------------------------------------------
__global__ void bias_kernel(const float* __restrict__ e0, const float* __restrict__ e1,
                            const float* __restrict__ e2, const float* __restrict__ me,
                            const float* __restrict__ Bp, int O, float* __restrict__ outB) {
  int idx = blockIdx.x * blockDim.x + threadIdx.x;
  int total = 3 * 1000 * O;
  if (idx >= total) return;
  int mode = idx / (1000 * O);
  int rem  = idx % (1000 * O);
  int n = rem / O, o = rem % O;
  const float* emb = (mode == 0) ? e0 : (mode == 1) ? e1 : e2;
  float s = 0.f;
#pragma unroll
  for (int d = 0; d < 16; ++d)
    s += emb[n * 16 + d] * me[mode * 16 + d] * Bp[d * O + o];
  outB[idx] = s;
}

// ---------------------------------------------------------------------------
// packW: Bt[(o*16+d)][k] = bf16(W[d,k,o]) k<240, else 0.
// ---------------------------------------------------------------------------
__global__ void packW_kernel(const float* __restrict__ Wg, const float* __restrict__ Wu,
                             u16* __restrict__ BtG, u16* __restrict__ BtU) {
  int idx = blockIdx.x * blockDim.x + threadIdx.x;
  if (idx >= (2048 + 1024) * 256) return;
  if (idx < 2048 * 256) {
    int col = idx >> 8, k = idx & 255;
    int o = col >> 4, d = col & 15;
    BtG[idx] = (k < 240) ? (u16)f2bf(Wg[d * 240 * 128 + k * 128 + o]) : (u16)0;
  } else {
    int i2 = idx - 2048 * 256;
    int col = i2 >> 8, k = i2 & 255;
    int o = col >> 4, d = col & 15;
    BtU[i2] = (k < 240) ? (u16)f2bf(Wu[d * 240 * 64 + k * 64 + o]) : (u16)0;
  }
}

// ---------------------------------------------------------------------------
// cheb_v3: D[f][n] = alpha * sum_k A[f][k]*S16[n][k] (+ beta*Res[f][n])
// A: [Mdim][1024] bf16 ; S16: [1024][1024] bf16 ; tile 128(f) x 64(n), BK=64.
// glds staging, XOR chunk swizzle (c ^ row&7). 256 thr = 4 waves x 32 rows.
// Epilogue: bf16 -> optional Yt[f][n]; packed 4-row chunks -> AgA (+AgX if c<16)
// flags: 1=hasRes, 2=hasY, 4=hasAgX
// ---------------------------------------------------------------------------
struct ChebArgs2 {
  const u16* S16[3]; const u16* A[3]; const u16* Res[3];
  u16* Yt[3]; u16* AgA[3]; u16* AgX[3];
};

__global__ __launch_bounds__(256) void cheb_v3(ChebArgs2 g, int fdiv, int agbase,
                                               float alpha, float beta, int flags) {
  const int mode = blockIdx.z;
  const u16* __restrict__ Ab = g.A[mode];
  const u16* __restrict__ Sb = g.S16[mode];

  __shared__ u16 As[128 * 64];
  __shared__ u16 Bs[64 * 64];

  const int t = threadIdx.x;
  const int row0 = blockIdx.y * 128, n0 = blockIdx.x * 64;
  const int lane = t & 63, wbase = t & 192;
  const int l16 = lane & 15, quad = lane >> 4;
  const int wm = (t >> 6) * 32;

  f32x4 acc[2][4];
#pragma unroll
  for (int a = 0; a < 2; ++a)
#pragma unroll
    for (int b = 0; b < 4; ++b) acc[a][b] = (f32x4){0.f, 0.f, 0.f, 0.f};

  for (int k0 = 0; k0 < 1024; k0 += 64) {
#pragma unroll
    for (int p = 0; p < 4; ++p) {  // A tile 128x64 = 1024 chunks
      int idx = p * 256 + t; int row = idx >> 3; int cd = (idx & 7) ^ (row & 7);
      glds16(Ab + (size_t)(row0 + row) * 1024 + k0 + cd * 8,
             &As[(size_t)(p * 256 + wbase) * 8]);
    }
#pragma unroll
    for (int p = 0; p < 2; ++p) {  // B tile 64x64 = 512 chunks
      int idx = p * 256 + t; int row = idx >> 3; int cd = (idx & 7) ^ (row & 7);
      glds16(Sb + (size_t)(n0 + row) * 1024 + k0 + cd * 8,
             &Bs[(size_t)(p * 256 + wbase) * 8]);
    }
    __syncthreads();
    s16x8 af[2][2], bfr[4][2];
#pragma unroll
    for (int mi = 0; mi < 2; ++mi) {
      int row = wm + mi * 16 + l16;
#pragma unroll
      for (int s = 0; s < 2; ++s) {
        int cl = (s * 4 + quad) ^ (row & 7);
        af[mi][s] = *(const s16x8*)&As[row * 64 + cl * 8];
      }
    }
#pragma unroll
    for (int ni = 0; ni < 4; ++ni) {
      int row = ni * 16 + l16;
#pragma unroll
      for (int s = 0; s < 2; ++s) {
        int cl = (s * 4 + quad) ^ (row & 7);
        bfr[ni][s] = *(const s16x8*)&Bs[row * 64 + cl * 8];
      }
    }
#pragma unroll
    for (int s = 0; s < 2; ++s)
#pragma unroll
      for (int mi = 0; mi < 2; ++mi)
#pragma unroll
        for (int ni = 0; ni < 4; ++ni)
          acc[mi][ni] = __builtin_amdgcn_mfma_f32_16x16x32_bf16(af[mi][s], bfr[ni][s], acc[mi][ni], 0, 0, 0);
    __syncthreads();
  }

#pragma unroll
  for (int mi = 0; mi < 2; ++mi) {
    int frow0 = row0 + wm + mi * 16 + quad * 4;
    int b = frow0 / fdiv, c0 = frow0 - b * fdiv;
#pragma unroll
    for (int ni = 0; ni < 4; ++ni) {
      int n = n0 + ni * 16 + l16;
      if (n < 1000) {
        u16 pk[4];
#pragma unroll
        for (int r = 0; r < 4; ++r) {
          float v = alpha * acc[mi][ni][r];
          if (flags & 1) v += beta * bf2f(g.Res[mode][(size_t)(frow0 + r) * 1024 + n]);
          u16 h = (u16)f2bf(v);
          pk[r] = h;
          if (flags & 2) g.Yt[mode][(size_t)(frow0 + r) * 1024 + n] = h;
        }
        u64 pv = (u64)pk[0] | ((u64)pk[1] << 16) | ((u64)pk[2] << 32) | ((u64)pk[3] << 48);
        *(u64*)&g.AgA[mode][(size_t)(n * 8 + b) * 256 + agbase + c0] = pv;
        if ((flags & 4) && c0 < 16)
          *(u64*)&g.AgX[mode][(size_t)(n * 8 + b) * 256 + agbase + c0] = pv;
      }
    }
  }
}

// ---------------------------------------------------------------------------
// meta2: G = A[8000x256] @ Bt[(O*16)x256]^T ; epilogue d-reduce with ew.
// Tile 128 rows x 64 G-cols, BK=32 (8 iters), glds staging, swizzle c^((row>>1)&3)
// gate: sigmoid -> ZSt bf16 + AgU[16+og] bf16 + Rb fp32 ; update: tanh -> out.
// ---------------------------------------------------------------------------
struct Meta2Args {
  const u16* Ag;        // read A  [3][8000][256]
  const u16* Bt;        // [O*16][256]
  const float* emb[3];
  const float* me;
  const float* Bias;    // [3][1000][O]
  const float* state[3];
  u16* ZSt;             // [3][512][1024]
  u16* AgU;             // [3][8000][256]
  float* Rb;            // [3][8000][64]
  float* out;
};

__global__ __launch_bounds__(256) void meta2(Meta2Args A, int is_gate, int O) {
  const int mode = blockIdx.z;
  const int row0 = blockIdx.y * 128;
  const int col0 = blockIdx.x * 64;
  const int n0 = row0 >> 3;

  __shared__ union UU {
    struct { u16 As[128 * 32]; u16 Bs[64 * 32]; } s;
    float Epi[128][65];
  } u;
  __shared__ float ewS[16][16];

  const int t = threadIdx.x;
  {
    int nl = t >> 4, d = t & 15;
    int n = n0 + nl;
    if (nl < 16) ewS[nl][d] = (n < 1000) ? A.emb[mode][n * 16 + d] * A.me[mode * 16 + d] : 0.f;
  }

  const u16* Agm = A.Ag + (size_t)mode * 2048000;
  const int lane = t & 63, wbase = t & 192;
  const int l16 = lane & 15, quad = lane >> 4;
  const int wm = (t >> 6) * 32;

  f32x4 acc[2][4];
#pragma unroll
  for (int a = 0; a < 2; ++a)
#pragma unroll
    for (int b = 0; b < 4; ++b) acc[a][b] = (f32x4){0.f, 0.f, 0.f, 0.f};

  for (int k0 = 0; k0 < 256; k0 += 32) {
#pragma unroll
    for (int p = 0; p < 2; ++p) {  // A tile 128x32 = 512 chunks
      int idx = p * 256 + t; int row = idx >> 2; int cd = (idx & 3) ^ ((row >> 1) & 3);
      int gr = row0 + row; if (gr > 7999) gr = 7999;
      glds16(Agm + (size_t)gr * 256 + k0 + cd * 8, &u.s.As[(size_t)(p * 256 + wbase) * 8]);
    }
    {  // B tile 64x32 = 256 chunks
      int row = t >> 2; int cd = (t & 3) ^ ((row >> 1) & 3);
      glds16(A.Bt + (size_t)(col0 + row) * 256 + k0 + cd * 8, &u.s.Bs[(size_t)wbase * 8]);
    }
    __syncthreads();
    s16x8 af[2], bfr[4];
#pragma unroll
    for (int mi = 0; mi < 2; ++mi) {
      int row = wm + mi * 16 + l16;
      int cl = quad ^ ((row >> 1) & 3);
      af[mi] = *(const s16x8*)&u.s.As[row * 32 + cl * 8];
    }
#pragma unroll
    for (int ni = 0; ni < 4; ++ni) {
      int row = ni * 16 + l16;
      int cl = quad ^ ((row >> 1) & 3);
      bfr[ni] = *(const s16x8*)&u.s.Bs[row * 32 + cl * 8];
    }
#pragma unroll
    for (int mi = 0; mi < 2; ++mi)
#pragma unroll
      for (int ni = 0; ni < 4; ++ni)
        acc[mi][ni] = __builtin_amdgcn_mfma_f32_16x16x32_bf16(af[mi], bfr[ni], acc[mi][ni], 0, 0, 0);
    __syncthreads();
  }

  // epilogue: scale by ew, dump to LDS, d-reduce
#pragma unroll
  for (int mi = 0; mi < 2; ++mi)
#pragma unroll
    for (int ni = 0; ni < 4; ++ni)
#pragma unroll
      for (int r = 0; r < 4; ++r) {
        int row = wm + mi * 16 + quad * 4 + r;
        u.Epi[row][ni * 16 + l16] = acc[mi][ni][r] * ewS[row >> 3][l16];
      }
  __syncthreads();

#pragma unroll
  for (int j = 0; j < 2; ++j) {
    int oi = t + j * 256;      // 128 rows x 4 o
    int row = oi >> 2;
    int ol = oi & 3;
    float s = 0.f;
#pragma unroll
    for (int d = 0; d < 16; ++d) s += u.Epi[row][ol * 16 + d];
    int gr = row0 + row;
    if (gr < 8000) {
      int n = gr >> 3, b = gr & 7;
      int og = (col0 >> 4) + ol;
      float pre = s + A.Bias[(size_t)mode * 1000 * O + n * O + og];
      if (is_gate) {
        float sg = 1.f / (1.f + __expf(-pre));
        if (og < 64) {
          float st = A.state[mode][(b * 1000 + n) * 64 + og];
          float zs = sg * st;
          A.ZSt[(size_t)mode * 524288 + (size_t)(b * 64 + og) * 1024 + n] = (u16)f2bf(zs);
          A.AgU[(size_t)mode * 2048000 + (size_t)gr * 256 + 16 + og] = (u16)f2bf(zs);
        } else {
          A.Rb[(size_t)mode * 512000 + gr * 64 + (og - 64)] = sg;
        }
      } else {
        float hc = tanhf(pre);
        float rr = A.Rb[(size_t)mode * 512000 + gr * 64 + og];
        float st = A.state[mode][(b * 1000 + n) * 64 + og];
        A.out[(size_t)mode * 512000 + (b * 1000 + n) * 64 + og] = rr * st + (1.f - rr) * hc;
      }
    }
  }
}

// ---------------------------------------------------------------------------
extern "C" void kernel_launch(void* const* d_in, const int* in_sizes, int n_in,
                              void* d_out, int out_size, void* d_ws, size_t ws_size,
                              hipStream_t stream) {
  const float* x[3]   = {(const float*)d_in[0], (const float*)d_in[1], (const float*)d_in[2]};
  const float* st[3]  = {(const float*)d_in[3], (const float*)d_in[4], (const float*)d_in[5]};
  const float* S[3]   = {(const float*)d_in[6], (const float*)d_in[7], (const float*)d_in[8]};
  const float* emb[3] = {(const float*)d_in[9], (const float*)d_in[10], (const float*)d_in[11]};
  const float* me = (const float*)d_in[12];
  const float* Wg = (const float*)d_in[13];
  const float* Bg = (const float*)d_in[14];
  const float* Wu = (const float*)d_in[15];
  const float* Bu = (const float*)d_in[16];
  float* out = (float*)d_out;

  // workspace carve-up (floats first, then bf16) — total ~55 MB
  float* BiG = (float*)d_ws;            // 3*1000*128
  float* BiU = BiG + 384000;            // 3*1000*64
  float* Rb  = BiU + 192000;            // 3*8000*64
  u16* S16 = (u16*)(Rb + 1536000);      // 3*1024*1024
  u16* Xt  = S16 + 3145728;             // 3*640*1024
  u16* T1t = Xt + 1966080;              // 3*640*1024
  u16* ZSt = T1t + 1966080;             // 3*512*1024
  u16* SZ1t= ZSt + 1572864;             // 3*512*1024
  u16* Ag  = SZ1t + 1572864;            // 3*8000*256
  u16* AgU = Ag + 6144000;              // 3*8000*256
  u16* BtG = AgU + 6144000;             // 2048*256
  u16* BtU = BtG + 524288;              // 1024*256

  {
    PrepArgs P;
    for (int m = 0; m < 3; ++m) { P.x[m] = x[m]; P.st[m] = st[m]; P.S[m] = S[m]; }
    P.S16 = S16; P.Xt = Xt; P.Ag = Ag; P.AgU = AgU; P.T1t = T1t; P.ZSt = ZSt; P.SZ1t = SZ1t;
    prep<<<32436, 256, 0, stream>>>(P);
  }
  bias_kernel<<<1500, 256, 0, stream>>>(emb[0], emb[1], emb[2], me, Bg, 128, BiG);
  bias_kernel<<<750, 256, 0, stream>>>(emb[0], emb[1], emb[2], me, Bu, 64, BiU);
  packW_kernel<<<3072, 256, 0, stream>>>(Wg, Wu, BtG, BtU);

  // cheb1: T1t = Xt @ S^T ; -> T1t + Ag[80..159] (+AgU x-part)
  {
    ChebArgs2 a;
    for (int m = 0; m < 3; ++m) {
      a.S16[m] = S16 + (size_t)m * 1048576; a.A[m] = Xt + (size_t)m * 655360;
      a.Res[m] = nullptr; a.Yt[m] = T1t + (size_t)m * 655360;
      a.AgA[m] = Ag + (size_t)m * 2048000; a.AgX[m] = AgU + (size_t)m * 2048000;
    }
    cheb_v3<<<dim3(16, 5, 3), 256, 0, stream>>>(a, 80, 80, 1.f, 0.f, 2 | 4);
  }
  // cheb2: T2t = 2*T1t @ S^T - Xt ; -> Ag[160..239] (+AgU x-part)
  {
    ChebArgs2 a;
    for (int m = 0; m < 3; ++m) {
      a.S16[m] = S16 + (size_t)m * 1048576; a.A[m] = T1t + (size_t)m * 655360;
      a.Res[m] = Xt + (size_t)m * 655360; a.Yt[m] = nullptr;
      a.AgA[m] = Ag + (size_t)m * 2048000; a.AgX[m] = AgU + (size_t)m * 2048000;
    }
    cheb_v3<<<dim3(16, 5, 3), 256, 0, stream>>>(a, 80, 160, 2.f, -1.f, 1 | 4);
  }
  // gate meta: reads Ag; writes ZSt + AgU[16..79] + Rb
  {
    Meta2Args a;
    a.Ag = Ag; a.Bt = BtG; a.me = me; a.Bias = BiG;
    a.ZSt = ZSt; a.AgU = AgU; a.Rb = Rb; a.out = out;
    for (int m = 0; m < 3; ++m) { a.emb[m] = emb[m]; a.state[m] = st[m]; }
    meta2<<<dim3(32, 63, 3), 256, 0, stream>>>(a, 1, 128);
  }
  // cheb3: SZ1t = ZSt @ S^T ; -> SZ1t + AgU[96..159]
  {
    ChebArgs2 a;
    for (int m = 0; m < 3; ++m) {
      a.S16[m] = S16 + (size_t)m * 1048576; a.A[m] = ZSt + (size_t)m * 524288;
      a.Res[m] = nullptr; a.Yt[m] = SZ1t + (size_t)m * 524288;
      a.AgA[m] = AgU + (size_t)m * 2048000; a.AgX[m] = nullptr;
    }
    cheb_v3<<<dim3(16, 4, 3), 256, 0, stream>>>(a, 64, 96, 1.f, 0.f, 2);
  }
  // cheb4: SZ2t = 2*SZ1t @ S^T - ZSt ; -> AgU[176..239]
  {
    ChebArgs2 a;
    for (int m = 0; m < 3; ++m) {
      a.S16[m] = S16 + (size_t)m * 1048576; a.A[m] = SZ1t + (size_t)m * 524288;
      a.Res[m] = ZSt + (size_t)m * 524288; a.Yt[m] = nullptr;
      a.AgA[m] = AgU + (size_t)m * 2048000; a.AgX[m] = nullptr;
    }
    cheb_v3<<<dim3(16, 4, 3), 256, 0, stream>>>(a, 64, 176, 2.f, -1.f, 1);
  }
  // update meta: reads AgU; writes out
  {
    Meta2Args a;
    a.Ag = AgU; a.Bt = BtU; a.me = me; a.Bias = BiU;
    a.ZSt = ZSt; a.AgU = AgU; a.Rb = Rb; a.out = out;
    for (int m = 0; m < 3; ++m) { a.emb[m] = emb[m]; a.state[m] = st[m]; }
    meta2<<<dim3(16, 63, 3), 256, 0, stream>>>(a, 0, 64);
  }
}

// Round 4
// 270.414 us; speedup vs baseline: 6.2027x; 1.2333x over previous
//
#include <hip/hip_runtime.h>
#include <math.h>

// ---------------------------------------------------------------------------
// HimNet multimode v4. B=8,N=1000,CIN=16,H=64,D=16,K=3,XIN=80,K*XIN=240,2H=128
//
// cheb GEMMs feature-major: T1t[f][n] = sum_k Xt[f][k]*S16[n][k], 64x64 tiles.
// meta GEMM: A[8000x256] (rows n*8+b, k=kc*80+c) vs Btd d-major
// (Btd[(d*O+o)][k] = W[d,k,o]); block = 64 rows, A resident in LDS with
// fragments hoisted to registers; loop over (d,oc) B-tiles; per-tile
// outacc += ew[n,d]*acc in registers (no LDS epilogue reduce).
// ---------------------------------------------------------------------------

typedef __attribute__((ext_vector_type(8))) short s16x8;
typedef __attribute__((ext_vector_type(4))) float f32x4;
typedef unsigned short u16;
typedef unsigned int u32;
typedef unsigned long long u64;

__device__ __forceinline__ u32 f2bf(float f) {
  union { float f; u32 u; } v; v.f = f;
  return (v.u + 0x7FFFu + ((v.u >> 16) & 1u)) >> 16;  // RNE
}
__device__ __forceinline__ float bf2f(u16 h) {
  union { u32 u; float f; } v; v.u = (u32)h << 16; return v.f;
}
__device__ __forceinline__ void glds16(const u16* g, u16* l) {
  __builtin_amdgcn_global_load_lds(
      (const __attribute__((address_space(1))) void*)g,
      (__attribute__((address_space(3))) void*)l, 16, 0, 0);
}

// ---------------------------------------------------------------------------
// prep: S16[3][1024][1024], Xt[3][640][1024], Ag kc0 slots, AgU x-slots,
// K-pads, n-pad rows of T1t/ZSt/SZ1t.
// ---------------------------------------------------------------------------
#define E0 3145728
#define E1 1966080
#define E2 1920000
#define E3 384000
#define E4 384000
#define E5 384000
#define E6 119808
// total = 8303616 = 32436 * 256

struct PrepArgs {
  const float* x[3]; const float* st[3]; const float* S[3];
  u16 *S16, *Xt, *Ag, *AgU, *T1t, *ZSt, *SZ1t;
};

__global__ void prep(PrepArgs P) {
  long idx = (long)blockIdx.x * 256 + threadIdx.x;
  if (idx < E0) {  // S16 incl pads
    int m = (int)(idx >> 20); int rem = (int)(idx & 1048575);
    int n = rem >> 10, k = rem & 1023;
    float v = (n < 1000 && k < 1000) ? P.S[m][n * 1000 + k] : 0.f;
    P.S16[(size_t)m * 1048576 + rem] = (u16)f2bf(v); return;
  }
  idx -= E0;
  if (idx < E1) {  // Xt incl n-pads
    int m = (int)(idx / 655360); int rem = (int)(idx % 655360);
    int col = rem >> 10, nn = rem & 1023;
    int b = col / 80, c = col % 80;
    float v = 0.f;
    if (nn < 1000) v = (c < 16) ? P.x[m][(b * 1000 + nn) * 16 + c]
                                : P.st[m][(b * 1000 + nn) * 64 + c - 16];
    P.Xt[(size_t)m * 655360 + rem] = (u16)f2bf(v); return;
  }
  idx -= E1;
  if (idx < E2) {  // Ag kc0 (cols 0..79)
    int m = (int)(idx / 640000); int rem = (int)(idx % 640000);
    int r = rem / 80, c = rem % 80;
    int n = r >> 3, b = r & 7;
    float v = (c < 16) ? P.x[m][(b * 1000 + n) * 16 + c]
                       : P.st[m][(b * 1000 + n) * 64 + c - 16];
    P.Ag[(size_t)m * 2048000 + (size_t)r * 256 + c] = (u16)f2bf(v); return;
  }
  idx -= E2;
  if (idx < E3) {  // Ag K-pad 240..255
    int m = (int)(idx / 128000); int rem = (int)(idx % 128000);
    int r = rem / 16, c = 240 + rem % 16;
    P.Ag[(size_t)m * 2048000 + (size_t)r * 256 + c] = 0; return;
  }
  idx -= E3;
  if (idx < E4) {  // AgU kc0 x-part (cols 0..15)
    int m = (int)(idx / 128000); int rem = (int)(idx % 128000);
    int r = rem / 16, c = rem % 16;
    int n = r >> 3, b = r & 7;
    P.AgU[(size_t)m * 2048000 + (size_t)r * 256 + c] =
        (u16)f2bf(P.x[m][(b * 1000 + n) * 16 + c]); return;
  }
  idx -= E4;
  if (idx < E5) {  // AgU K-pad
    int m = (int)(idx / 128000); int rem = (int)(idx % 128000);
    int r = rem / 16, c = 240 + rem % 16;
    P.AgU[(size_t)m * 2048000 + (size_t)r * 256 + c] = 0; return;
  }
  idx -= E5;
  if (idx < E6) {  // n-pad rows (k=1000..1023) of T1t/ZSt/SZ1t
    int m = (int)(idx / 39936); int rem = (int)(idx % 39936);
    if (rem < 15360) { int col = rem / 24, j = rem % 24;
      P.T1t[(size_t)m * 655360 + col * 1024 + 1000 + j] = 0; }
    else if (rem < 27648) { int e = rem - 15360; int col = e / 24, j = e % 24;
      P.ZSt[(size_t)m * 524288 + col * 1024 + 1000 + j] = 0; }
    else { int e = rem - 27648; int col = e / 24, j = e % 24;
      P.SZ1t[(size_t)m * 524288 + col * 1024 + 1000 + j] = 0; }
    return;
  }
}

// ---------------------------------------------------------------------------
// bias: outB[mode][n*O+o] = sum_d emb[n,d]*me[mode,d]*Bp[d,o]
// ---------------------------------------------------------------------------
__global__ void bias_kernel(const float* __restrict__ e0, const float* __restrict__ e1,
                            const float* __restrict__ e2, const float* __restrict__ me,
                            const float* __restrict__ Bp, int O, float* __restrict__ outB) {
  int idx = blockIdx.x * blockDim.x + threadIdx.x;
  int total = 3 * 1000 * O;
  if (idx >= total) return;
  int mode = idx / (1000 * O);
  int rem  = idx % (1000 * O);
  int n = rem / O, o = rem % O;
  const float* emb = (mode == 0) ? e0 : (mode == 1) ? e1 : e2;
  float s = 0.f;
#pragma unroll
  for (int d = 0; d < 16; ++d)
    s += emb[n * 16 + d] * me[mode * 16 + d] * Bp[d * O + o];
  outB[idx] = s;
}

// ---------------------------------------------------------------------------
// packW (d-major): Bt[(d*O+o)][k] = bf16(W[d,k,o]) k<240, else 0.
// ---------------------------------------------------------------------------
__global__ void packW_kernel(const float* __restrict__ Wg, const float* __restrict__ Wu,
                             u16* __restrict__ BtG, u16* __restrict__ BtU) {
  int idx = blockIdx.x * blockDim.x + threadIdx.x;
  if (idx >= (2048 + 1024) * 256) return;
  if (idx < 2048 * 256) {
    int col = idx >> 8, k = idx & 255;
    int d = col >> 7, o = col & 127;
    BtG[idx] = (k < 240) ? (u16)f2bf(Wg[d * 30720 + k * 128 + o]) : (u16)0;
  } else {
    int i2 = idx - 2048 * 256;
    int col = i2 >> 8, k = i2 & 255;
    int d = col >> 6, o = col & 63;
    BtU[i2] = (k < 240) ? (u16)f2bf(Wu[d * 15360 + k * 64 + o]) : (u16)0;
  }
}

// ---------------------------------------------------------------------------
// cheb_v4: D[f][n] = alpha*sum_k A[f][k]*S16[n][k] (+beta*Res[f][n])
// Tile 64(f) x 64(n), BK=64, 256 thr = 4 waves in 2x2 grid (32x32 each).
// glds staging, XOR chunk swizzle c^(row&7). flags: 1=hasRes,2=hasY,4=hasAgX
// ---------------------------------------------------------------------------
struct ChebArgs2 {
  const u16* S16[3]; const u16* A[3]; const u16* Res[3];
  u16* Yt[3]; u16* AgA[3]; u16* AgX[3];
};

__global__ __launch_bounds__(256, 2) void cheb_v4(ChebArgs2 g, int fdiv, int agbase,
                                                  float alpha, float beta, int flags) {
  const int mode = blockIdx.z;
  const u16* __restrict__ Ab = g.A[mode];
  const u16* __restrict__ Sb = g.S16[mode];

  __shared__ u16 As[64 * 64];
  __shared__ u16 Bs[64 * 64];

  const int t = threadIdx.x;
  const int row0 = blockIdx.y * 64, n0 = blockIdx.x * 64;
  const int lane = t & 63, wid = t >> 6;
  const int l16 = lane & 15, quad = lane >> 4;
  const int wy = (wid >> 1) * 32, wx = (wid & 1) * 32;

  f32x4 acc[2][2];
#pragma unroll
  for (int a = 0; a < 2; ++a)
#pragma unroll
    for (int b = 0; b < 2; ++b) acc[a][b] = (f32x4){0.f, 0.f, 0.f, 0.f};

  for (int k0 = 0; k0 < 1024; k0 += 64) {
#pragma unroll
    for (int p = 0; p < 2; ++p) {  // A: 64x64 = 512 chunks
      int idx = p * 256 + t; int row = idx >> 3; int cs = (idx & 7) ^ (row & 7);
      glds16(Ab + (size_t)(row0 + row) * 1024 + k0 + cs * 8, &As[idx * 8]);
    }
#pragma unroll
    for (int p = 0; p < 2; ++p) {  // B: 64x64 = 512 chunks
      int idx = p * 256 + t; int row = idx >> 3; int cs = (idx & 7) ^ (row & 7);
      glds16(Sb + (size_t)(n0 + row) * 1024 + k0 + cs * 8, &Bs[idx * 8]);
    }
    __syncthreads();
    s16x8 af[2][2], bf[2][2];
#pragma unroll
    for (int mi = 0; mi < 2; ++mi) {
      int row = wy + mi * 16 + l16;
#pragma unroll
      for (int ks = 0; ks < 2; ++ks) {
        int cl = (ks * 4 + quad) ^ (row & 7);
        af[mi][ks] = *(const s16x8*)&As[row * 64 + cl * 8];
      }
    }
#pragma unroll
    for (int ni = 0; ni < 2; ++ni) {
      int row = wx + ni * 16 + l16;
#pragma unroll
      for (int ks = 0; ks < 2; ++ks) {
        int cl = (ks * 4 + quad) ^ (row & 7);
        bf[ni][ks] = *(const s16x8*)&Bs[row * 64 + cl * 8];
      }
    }
#pragma unroll
    for (int ks = 0; ks < 2; ++ks)
#pragma unroll
      for (int mi = 0; mi < 2; ++mi)
#pragma unroll
        for (int ni = 0; ni < 2; ++ni)
          acc[mi][ni] = __builtin_amdgcn_mfma_f32_16x16x32_bf16(af[mi][ks], bf[ni][ks], acc[mi][ni], 0, 0, 0);
    __syncthreads();
  }

#pragma unroll
  for (int mi = 0; mi < 2; ++mi) {
    int frow0 = row0 + wy + mi * 16 + quad * 4;
    int b = frow0 / fdiv, c0 = frow0 - b * fdiv;
#pragma unroll
    for (int ni = 0; ni < 2; ++ni) {
      int n = n0 + wx + ni * 16 + l16;
      if (n < 1000) {
        u16 pk[4];
#pragma unroll
        for (int r = 0; r < 4; ++r) {
          float v = alpha * acc[mi][ni][r];
          if (flags & 1) v += beta * bf2f(g.Res[mode][(size_t)(frow0 + r) * 1024 + n]);
          u16 h = (u16)f2bf(v);
          pk[r] = h;
          if (flags & 2) g.Yt[mode][(size_t)(frow0 + r) * 1024 + n] = h;
        }
        u64 pv = (u64)pk[0] | ((u64)pk[1] << 16) | ((u64)pk[2] << 32) | ((u64)pk[3] << 48);
        *(u64*)&g.AgA[mode][(size_t)(n * 8 + b) * 256 + agbase + c0] = pv;
        if ((flags & 4) && c0 < 16)
          *(u64*)&g.AgX[mode][(size_t)(n * 8 + b) * 256 + agbase + c0] = pv;
      }
    }
  }
}

// ---------------------------------------------------------------------------
// meta3: out[r,o] = act( sum_d ew[n,d] * (A[r,:] . Btd[d*O+o,:]) + bias[n,o] )
// Block: 64 rows (8 nodes), A resident in LDS, frags hoisted to regs.
// Loop over (d,oc) tiles of 64 B-rows; outacc += ew*acc in registers.
// 4 waves 2x2 (32 rows x 32 cols each). LDS 64.5KB -> 2 blocks/CU.
// ---------------------------------------------------------------------------
struct Meta3Args {
  const u16* Ag;        // [3][8000][256]
  const u16* Bt;        // [O*16][256] d-major
  const float* emb[3];
  const float* me;
  const float* Bias;    // [3][1000][O]
  const float* state[3];
  u16* ZSt;             // [3][512][1024]
  u16* AgU;             // [3][8000][256]
  float* Rb;            // [3][8000][64]
  float* out;
};

__global__ __launch_bounds__(256, 2) void meta3(Meta3Args A, int is_gate, int O) {
  const int mode = blockIdx.z;
  const int row0 = blockIdx.y * 64;
  const int n0 = row0 >> 3;

  __shared__ u16 As[64 * 256];   // 32KB, swizzled
  __shared__ u16 Bs[64 * 256];   // 32KB, swizzled
  __shared__ float ewS[8][17];

  const int t = threadIdx.x;
  if (t < 128) {
    int nl = t >> 4, d = t & 15;
    ewS[nl][d] = A.emb[mode][(n0 + nl) * 16 + d] * A.me[mode * 16 + d];
  }

  const int lane = t & 63, wid = t >> 6;
  const int l16 = lane & 15, quad = lane >> 4;
  const int wy = (wid >> 1) * 32, wx = (wid & 1) * 32;
  const u16* Agm = A.Ag + (size_t)mode * 2048000;

  // stage A rows [row0,row0+64) x K256: 2048 chunks, 8 glds/thread
#pragma unroll
  for (int p = 0; p < 8; ++p) {
    int idx = p * 256 + t; int row = idx >> 5; int cs = (idx & 31) ^ (row & 7);
    glds16(Agm + (size_t)(row0 + row) * 256 + cs * 8, &As[idx * 8]);
  }
  __syncthreads();

  // hoist A fragments: afr[mi][ki] (64 VGPRs)
  s16x8 afr[2][8];
#pragma unroll
  for (int mi = 0; mi < 2; ++mi) {
    int row = wy + mi * 16 + l16;
#pragma unroll
    for (int ki = 0; ki < 8; ++ki) {
      int cl = (ki * 4 + quad) ^ (row & 7);
      afr[mi][ki] = *(const s16x8*)&As[row * 256 + cl * 8];
    }
  }

  f32x4 outacc[2][2][2];  // [oc][mi][ni]
#pragma unroll
  for (int a = 0; a < 2; ++a)
#pragma unroll
    for (int b = 0; b < 2; ++b)
#pragma unroll
      for (int c = 0; c < 2; ++c) outacc[a][b][c] = (f32x4){0.f, 0.f, 0.f, 0.f};

  const int shift = (O == 128) ? 1 : 0;
  const int ntiles = O >> 2;   // (O*16)/64

  for (int tl = 0; tl < ntiles; ++tl) {
    const int d = tl >> shift;
    const int oc = tl & shift;   // shift==1 -> tl&1 ; shift==0 -> 0
    __syncthreads();             // prev tile's Bs reads done
    const int brow0 = d * O + oc * 64;
#pragma unroll
    for (int p = 0; p < 8; ++p) {
      int idx = p * 256 + t; int row = idx >> 5; int cs = (idx & 31) ^ (row & 7);
      glds16(A.Bt + (size_t)(brow0 + row) * 256 + cs * 8, &Bs[idx * 8]);
    }
    __syncthreads();

    f32x4 acc[2][2];
#pragma unroll
    for (int a = 0; a < 2; ++a)
#pragma unroll
      for (int b = 0; b < 2; ++b) acc[a][b] = (f32x4){0.f, 0.f, 0.f, 0.f};

#pragma unroll
    for (int ki = 0; ki < 8; ++ki) {
      s16x8 bfr[2];
#pragma unroll
      for (int ni = 0; ni < 2; ++ni) {
        int row = wx + ni * 16 + l16;
        int cl = (ki * 4 + quad) ^ (row & 7);
        bfr[ni] = *(const s16x8*)&Bs[row * 256 + cl * 8];
      }
#pragma unroll
      for (int mi = 0; mi < 2; ++mi)
#pragma unroll
        for (int ni = 0; ni < 2; ++ni)
          acc[mi][ni] = __builtin_amdgcn_mfma_f32_16x16x32_bf16(afr[mi][ki], bfr[ni], acc[mi][ni], 0, 0, 0);
    }

    // fold d: outacc += ew[n,d] * acc
#pragma unroll
    for (int mi = 0; mi < 2; ++mi) {
      int nl = (wy + mi * 16 + quad * 4) >> 3;
      float s = ewS[nl][d];
#pragma unroll
      for (int ni = 0; ni < 2; ++ni)
#pragma unroll
        for (int r = 0; r < 4; ++r)
          outacc[oc][mi][ni][r] += s * acc[mi][ni][r];
    }
  }

  // epilogue: bias + activation + store, straight from registers
#pragma unroll
  for (int oc = 0; oc <= shift; ++oc)
#pragma unroll
    for (int mi = 0; mi < 2; ++mi)
#pragma unroll
      for (int ni = 0; ni < 2; ++ni)
#pragma unroll
        for (int r = 0; r < 4; ++r) {
          int row = row0 + wy + mi * 16 + quad * 4 + r;
          int n = row >> 3, b = row & 7;
          int o = oc * 64 + wx + ni * 16 + l16;
          float pre = outacc[oc][mi][ni][r] + A.Bias[(size_t)mode * 1000 * O + n * O + o];
          if (is_gate) {
            float sg = 1.f / (1.f + __expf(-pre));
            if (o < 64) {
              float st = A.state[mode][(b * 1000 + n) * 64 + o];
              float zs = sg * st;
              A.ZSt[(size_t)mode * 524288 + (size_t)(b * 64 + o) * 1024 + n] = (u16)f2bf(zs);
              A.AgU[(size_t)mode * 2048000 + (size_t)row * 256 + 16 + o] = (u16)f2bf(zs);
            } else {
              A.Rb[(size_t)mode * 512000 + row * 64 + (o - 64)] = sg;
            }
          } else {
            float hc = tanhf(pre);
            float rr = A.Rb[(size_t)mode * 512000 + row * 64 + o];
            float st = A.state[mode][(b * 1000 + n) * 64 + o];
            A.out[(size_t)mode * 512000 + (b * 1000 + n) * 64 + o] = rr * st + (1.f - rr) * hc;
          }
        }
}

// ---------------------------------------------------------------------------
extern "C" void kernel_launch(void* const* d_in, const int* in_sizes, int n_in,
                              void* d_out, int out_size, void* d_ws, size_t ws_size,
                              hipStream_t stream) {
  const float* x[3]   = {(const float*)d_in[0], (const float*)d_in[1], (const float*)d_in[2]};
  const float* st[3]  = {(const float*)d_in[3], (const float*)d_in[4], (const float*)d_in[5]};
  const float* S[3]   = {(const float*)d_in[6], (const float*)d_in[7], (const float*)d_in[8]};
  const float* emb[3] = {(const float*)d_in[9], (const float*)d_in[10], (const float*)d_in[11]};
  const float* me = (const float*)d_in[12];
  const float* Wg = (const float*)d_in[13];
  const float* Bg = (const float*)d_in[14];
  const float* Wu = (const float*)d_in[15];
  const float* Bu = (const float*)d_in[16];
  float* out = (float*)d_out;

  float* BiG = (float*)d_ws;            // 3*1000*128
  float* BiU = BiG + 384000;            // 3*1000*64
  float* Rb  = BiU + 192000;            // 3*8000*64
  u16* S16 = (u16*)(Rb + 1536000);      // 3*1024*1024
  u16* Xt  = S16 + 3145728;             // 3*640*1024
  u16* T1t = Xt + 1966080;              // 3*640*1024
  u16* ZSt = T1t + 1966080;             // 3*512*1024
  u16* SZ1t= ZSt + 1572864;             // 3*512*1024
  u16* Ag  = SZ1t + 1572864;            // 3*8000*256
  u16* AgU = Ag + 6144000;              // 3*8000*256
  u16* BtG = AgU + 6144000;             // 2048*256
  u16* BtU = BtG + 524288;              // 1024*256

  {
    PrepArgs P;
    for (int m = 0; m < 3; ++m) { P.x[m] = x[m]; P.st[m] = st[m]; P.S[m] = S[m]; }
    P.S16 = S16; P.Xt = Xt; P.Ag = Ag; P.AgU = AgU; P.T1t = T1t; P.ZSt = ZSt; P.SZ1t = SZ1t;
    prep<<<32436, 256, 0, stream>>>(P);
  }
  bias_kernel<<<1500, 256, 0, stream>>>(emb[0], emb[1], emb[2], me, Bg, 128, BiG);
  bias_kernel<<<750, 256, 0, stream>>>(emb[0], emb[1], emb[2], me, Bu, 64, BiU);
  packW_kernel<<<3072, 256, 0, stream>>>(Wg, Wu, BtG, BtU);

  // cheb1: T1t = Xt @ S^T -> T1t + Ag[80..159] (+AgU x-part)
  {
    ChebArgs2 a;
    for (int m = 0; m < 3; ++m) {
      a.S16[m] = S16 + (size_t)m * 1048576; a.A[m] = Xt + (size_t)m * 655360;
      a.Res[m] = nullptr; a.Yt[m] = T1t + (size_t)m * 655360;
      a.AgA[m] = Ag + (size_t)m * 2048000; a.AgX[m] = AgU + (size_t)m * 2048000;
    }
    cheb_v4<<<dim3(16, 10, 3), 256, 0, stream>>>(a, 80, 80, 1.f, 0.f, 2 | 4);
  }
  // cheb2: T2t = 2*T1t @ S^T - Xt -> Ag[160..239] (+AgU x-part)
  {
    ChebArgs2 a;
    for (int m = 0; m < 3; ++m) {
      a.S16[m] = S16 + (size_t)m * 1048576; a.A[m] = T1t + (size_t)m * 655360;
      a.Res[m] = Xt + (size_t)m * 655360; a.Yt[m] = nullptr;
      a.AgA[m] = Ag + (size_t)m * 2048000; a.AgX[m] = AgU + (size_t)m * 2048000;
    }
    cheb_v4<<<dim3(16, 10, 3), 256, 0, stream>>>(a, 80, 160, 2.f, -1.f, 1 | 4);
  }
  // gate meta: reads Ag; writes ZSt + AgU[16..79] + Rb
  {
    Meta3Args a;
    a.Ag = Ag; a.Bt = BtG; a.me = me; a.Bias = BiG;
    a.ZSt = ZSt; a.AgU = AgU; a.Rb = Rb; a.out = out;
    for (int m = 0; m < 3; ++m) { a.emb[m] = emb[m]; a.state[m] = st[m]; }
    meta3<<<dim3(1, 125, 3), 256, 0, stream>>>(a, 1, 128);
  }
  // cheb3: SZ1t = ZSt @ S^T -> SZ1t + AgU[96..159]
  {
    ChebArgs2 a;
    for (int m = 0; m < 3; ++m) {
      a.S16[m] = S16 + (size_t)m * 1048576; a.A[m] = ZSt + (size_t)m * 524288;
      a.Res[m] = nullptr; a.Yt[m] = SZ1t + (size_t)m * 524288;
      a.AgA[m] = AgU + (size_t)m * 2048000; a.AgX[m] = nullptr;
    }
    cheb_v4<<<dim3(16, 8, 3), 256, 0, stream>>>(a, 64, 96, 1.f, 0.f, 2);
  }
  // cheb4: SZ2t = 2*SZ1t @ S^T - ZSt -> AgU[176..239]
  {
    ChebArgs2 a;
    for (int m = 0; m < 3; ++m) {
      a.S16[m] = S16 + (size_t)m * 1048576; a.A[m] = SZ1t + (size_t)m * 524288;
      a.Res[m] = ZSt + (size_t)m * 524288; a.Yt[m] = nullptr;
      a.AgA[m] = AgU + (size_t)m * 2048000; a.AgX[m] = nullptr;
    }
    cheb_v4<<<dim3(16, 8, 3), 256, 0, stream>>>(a, 64, 176, 2.f, -1.f, 1);
  }
  // update meta: reads AgU; writes out
  {
    Meta3Args a;
    a.Ag = AgU; a.Bt = BtU; a.me = me; a.Bias = BiU;
    a.ZSt = ZSt; a.AgU = AgU; a.Rb = Rb; a.out = out;
    for (int m = 0; m < 3; ++m) { a.emb[m] = emb[m]; a.state[m] = st[m]; }
    meta3<<<dim3(1, 125, 3), 256, 0, stream>>>(a, 0, 64);
  }
}